// Round 1
// baseline (713.638 us; speedup 1.0000x reference)
//
#include <hip/hip_runtime.h>
#include <hip/hip_bf16.h>

// ---- static problem geometry (from reference: IMAGE_SIZES // 14) ----
// hp x wp per image: (110,110)(80,110)(110,64)(56,90)(108,108)(110,80)(64,64)(90,110)
// token counts: 12100 8800 7040 5040 11664 8800 4096 9900  -> 67440
// merged (n/4): 3025 2200 1760 1260 2916 2200 1024 2475    -> 16860
#define MTOK  16860
#define MPAD  16896   // 132 * 128
#define NOUT  1024
#define KDIM  4096

__device__ __constant__ int c_mend[8] = {3025,5225,6985,8245,11161,13361,14385,16860};
__device__ __constant__ int c_moff[8] = {0,3025,5225,6985,8245,11161,13361,14385};
__device__ __constant__ int c_foff[8] = {0,12100,20900,27940,32980,44644,53444,57540};
__device__ __constant__ int c_wp[8]   = {110,110,64,90,108,80,64,110};

typedef __attribute__((ext_vector_type(8))) short  bf16x8;  // 8 bf16 = 4 VGPRs
typedef __attribute__((ext_vector_type(4))) float  f32x4;

__device__ __forceinline__ unsigned short f2bf(float f) {
    unsigned int u = __float_as_uint(f);
    u += 0x7FFFu + ((u >> 16) & 1u);   // round-to-nearest-even
    return (unsigned short)(u >> 16);
}

__device__ __forceinline__ void async_copy16(const void* g, void* l) {
    __builtin_amdgcn_global_load_lds(
        (const __attribute__((address_space(1))) void*)g,
        (__attribute__((address_space(3))) void*)l, 16, 0, 0);
}

// ---- kernel 1: 2x2 patch merge + fp32->bf16 cast ----
// merged[t][d*4 + ki*2 + kj] = feats[foff + (2i+ki)*wp + (2j+kj)][d]
__global__ __launch_bounds__(256) void merge_cast(const float* __restrict__ feats,
                                                  unsigned short* __restrict__ merged) {
    int t = blockIdx.x;                       // merged token 0..16859
    int d = blockIdx.y * 256 + threadIdx.x;   // 0..1023
    int im = 0;
    while (t >= c_mend[im]) im++;
    int r   = t - c_moff[im];
    int wp  = c_wp[im];
    int wp2 = wp >> 1;
    int i = r / wp2, j = r - i * wp2;
    size_t base = (size_t)(c_foff[im] + (2*i)*wp + 2*j) * 1024 + d;
    float a00 = feats[base];
    float a01 = feats[base + 1024];
    float a10 = feats[base + (size_t)wp * 1024];
    float a11 = feats[base + (size_t)wp * 1024 + 1024];
    ushort4 v = make_ushort4(f2bf(a00), f2bf(a01), f2bf(a10), f2bf(a11));
    *(ushort4*)(merged + (size_t)t * 4096 + d * 4) = v;
}

// ---- kernel 2: weight fp32 -> bf16 (already [N][K] row-major = B^T) ----
__global__ __launch_bounds__(256) void cast_w(const float* __restrict__ W,
                                              unsigned short* __restrict__ Wb) {
    size_t g = (size_t)(blockIdx.x * 256 + threadIdx.x) * 4;
    float4 v = *(const float4*)(W + g);
    *(ushort4*)(Wb + g) = make_ushort4(f2bf(v.x), f2bf(v.y), f2bf(v.z), f2bf(v.w));
}

// ---- kernel 3: C[M,N] = A[M,K] * B[N,K]^T, bf16 in, fp32 out (m97 structure) ----
#define BM 128
#define BN 128
#define BK 32
__global__ __launch_bounds__(256) void gemm_bt(const unsigned short* __restrict__ A,
                                               const unsigned short* __restrict__ B,
                                               float* __restrict__ C) {
    __shared__ unsigned short lA[BM * BK];   // 8 KiB, unpadded (global_load_lds layout)
    __shared__ unsigned short lB[BN * BK];   // 8 KiB

    const int bm = blockIdx.x, bn = blockIdx.y;
    const int tid  = threadIdx.x;
    const int wave = tid >> 6, lane = tid & 63;
    const int wm = (wave >> 1) * 64, wn = (wave & 1) * 64;

    const int lrow = lane >> 2;          // 0..15
    const int lcol = (lane & 3) * 8;     // 0,8,16,24 (bf16 elems)

    const unsigned short* Abase = A + (size_t)bm * 128 * KDIM;
    const unsigned short* Bbase = B + (size_t)bn * 128 * KDIM;

    f32x4 acc[4][4];
#pragma unroll
    for (int i = 0; i < 4; ++i)
#pragma unroll
        for (int j = 0; j < 4; ++j) acc[i][j] = (f32x4){0.f, 0.f, 0.f, 0.f};

    const int mrow = lane & 15;
    const int kq   = (lane >> 4) * 8;    // 0,8,16,24

    for (int k0 = 0; k0 < KDIM; k0 += BK) {
#pragma unroll
        for (int r = 0; r < 2; ++r) {
            int chunk = wave + r * 4;            // 0..7 (1 KiB LDS chunks)
            int row   = chunk * 16 + lrow;       // 0..127
            async_copy16(Abase + (size_t)row * KDIM + k0 + lcol, &lA[chunk * 512 + lane * 8]);
            async_copy16(Bbase + (size_t)row * KDIM + k0 + lcol, &lB[chunk * 512 + lane * 8]);
        }
        __syncthreads();   // drains vmcnt (global_load_lds) + orders LDS

        bf16x8 af[4], bfr[4];
#pragma unroll
        for (int i = 0; i < 4; ++i) {
            af[i]  = *(const bf16x8*)&lA[(wm + i * 16 + mrow) * BK + kq];
            bfr[i] = *(const bf16x8*)&lB[(wn + i * 16 + mrow) * BK + kq];
        }
#pragma unroll
        for (int i = 0; i < 4; ++i)
#pragma unroll
            for (int j = 0; j < 4; ++j)
                acc[i][j] = __builtin_amdgcn_mfma_f32_16x16x32_bf16(af[i], bfr[j], acc[i][j], 0, 0, 0);
        __syncthreads();   // protect LDS before next stage
    }

    // epilogue: C/D layout col=lane&15, row=(lane>>4)*4+reg
    const int col   = lane & 15;
    const int rquad = (lane >> 4) * 4;
#pragma unroll
    for (int i = 0; i < 4; ++i) {
        int gm0 = bm * 128 + wm + i * 16 + rquad;
#pragma unroll
        for (int j = 0; j < 4; ++j) {
            int gn = bn * 128 + wn + j * 16 + col;
#pragma unroll
            for (int rg = 0; rg < 4; ++rg) {
                int gm = gm0 + rg;
                if (gm < MTOK) C[(size_t)gm * NOUT + gn] = acc[i][j][rg];
            }
        }
    }
}

// ---- fallback (ws too small): exact fp32, slow but correct ----
__global__ __launch_bounds__(256) void naive_fb(const float* __restrict__ feats,
                                                const float* __restrict__ W,
                                                float* __restrict__ out) {
    int t = blockIdx.x;
    int o = blockIdx.y * 256 + threadIdx.x;
    int im = 0;
    while (t >= c_mend[im]) im++;
    int r = t - c_moff[im];
    int wp = c_wp[im], wp2 = wp >> 1;
    int i = r / wp2, j = r - i * wp2;
    const float* f00 = feats + (size_t)(c_foff[im] + (2*i)*wp + 2*j) * 1024;
    const float* f10 = f00 + (size_t)wp * 1024;
    const float* w = W + (size_t)o * 4096;
    float s = 0.f;
    for (int d = 0; d < 1024; ++d)
        s += f00[d] * w[d*4] + f00[d+1024] * w[d*4+1] + f10[d] * w[d*4+2] + f10[d+1024] * w[d*4+3];
    out[(size_t)t * 1024 + o] = s;
}

extern "C" void kernel_launch(void* const* d_in, const int* in_sizes, int n_in,
                              void* d_out, int out_size, void* d_ws, size_t ws_size,
                              hipStream_t stream) {
    const float* feats = (const float*)d_in[0];   // [67440, 1024] fp32
    const float* W     = (const float*)d_in[1];   // [1024, 4096] fp32
    float* out         = (float*)d_out;           // [16860, 1024] fp32

    const size_t need = ((size_t)MPAD + 1024) * KDIM * sizeof(unsigned short); // ~147 MB
    if (ws_size >= need) {
        unsigned short* merged = (unsigned short*)d_ws;          // [MPAD, 4096] bf16
        unsigned short* Wb     = merged + (size_t)MPAD * KDIM;   // [1024, 4096] bf16
        merge_cast<<<dim3(MTOK, 4), 256, 0, stream>>>(feats, merged);
        cast_w<<<dim3((NOUT * KDIM / 4) / 256), 256, 0, stream>>>(W, Wb);
        gemm_bt<<<dim3(MPAD / BM, NOUT / BN), 256, 0, stream>>>(merged, Wb, out);
    } else {
        naive_fb<<<dim3(MTOK, 4), 256, 0, stream>>>(feats, W, out);
    }
}

// Round 2
// 711.735 us; speedup vs baseline: 1.0027x; 1.0027x over previous
//
#include <hip/hip_runtime.h>
#include <hip/hip_bf16.h>

// ---- static problem geometry (from reference: IMAGE_SIZES // 14) ----
// hp x wp per image: (110,110)(80,110)(110,64)(56,90)(108,108)(110,80)(64,64)(90,110)
// token counts: 12100 8800 7040 5040 11664 8800 4096 9900  -> 67440
// merged (n/4): 3025 2200 1760 1260 2916 2200 1024 2475    -> 16860
#define MTOK  16860
#define MPAD  16896   // 132 * 128
#define NOUT  1024
#define KDIM  4096

__device__ __constant__ int c_mend[8] = {3025,5225,6985,8245,11161,13361,14385,16860};
__device__ __constant__ int c_moff[8] = {0,3025,5225,6985,8245,11161,13361,14385};
__device__ __constant__ int c_foff[8] = {0,12100,20900,27940,32980,44644,53444,57540};
__device__ __constant__ int c_wp[8]   = {110,110,64,90,108,80,64,110};

typedef __attribute__((ext_vector_type(8))) short          bf16x8;  // 8 bf16 = 4 VGPRs
typedef __attribute__((ext_vector_type(8))) unsigned short u16x8;
typedef __attribute__((ext_vector_type(4))) float          f32x4;

__device__ __forceinline__ unsigned short f2bf(float f) {
    unsigned int u = __float_as_uint(f);
    u += 0x7FFFu + ((u >> 16) & 1u);   // round-to-nearest-even
    return (unsigned short)(u >> 16);
}

__device__ __forceinline__ void async_copy16(const void* g, void* l) {
    __builtin_amdgcn_global_load_lds(
        (const __attribute__((address_space(1))) void*)g,
        (__attribute__((address_space(3))) void*)l, 16, 0, 0);
}

// ---- kernel 1: 2x2 patch merge + fp32->bf16 cast ----
// merged[t][d*4 + ki*2 + kj] = feats[foff + (2i+ki)*wp + (2j+kj)][d]
// One block handles 4 merged tokens; thread tid covers d = tid*4..tid*4+3,
// writing 16 contiguous bf16 (32 B) per token.
__global__ __launch_bounds__(256) void merge_cast(const float* __restrict__ feats,
                                                  unsigned short* __restrict__ merged) {
    const int d = threadIdx.x * 4;
#pragma unroll
    for (int it = 0; it < 4; ++it) {
        int t = blockIdx.x * 4 + it;
        if (t >= MTOK) return;
        int im = 0;
        while (t >= c_mend[im]) im++;
        int r   = t - c_moff[im];
        int wp  = c_wp[im];
        int wp2 = wp >> 1;
        int i = r / wp2, j = r - i * wp2;
        const float* p00 = feats + (size_t)(c_foff[im] + (2*i)*wp + 2*j) * 1024;
        const float* p01 = p00 + 1024;
        const float* p10 = p00 + (size_t)wp * 1024;
        const float* p11 = p10 + 1024;
        float4 a = *(const float4*)(p00 + d);
        float4 b = *(const float4*)(p01 + d);
        float4 c = *(const float4*)(p10 + d);
        float4 e = *(const float4*)(p11 + d);
        u16x8 lo, hi;
        lo[0]=f2bf(a.x); lo[1]=f2bf(b.x); lo[2]=f2bf(c.x); lo[3]=f2bf(e.x);
        lo[4]=f2bf(a.y); lo[5]=f2bf(b.y); lo[6]=f2bf(c.y); lo[7]=f2bf(e.y);
        hi[0]=f2bf(a.z); hi[1]=f2bf(b.z); hi[2]=f2bf(c.z); hi[3]=f2bf(e.z);
        hi[4]=f2bf(a.w); hi[5]=f2bf(b.w); hi[6]=f2bf(c.w); hi[7]=f2bf(e.w);
        unsigned short* o = merged + (size_t)t * 4096 + d * 4;
        *(u16x8*)(o)     = lo;
        *(u16x8*)(o + 8) = hi;
    }
}

// ---- kernel 2: weight fp32 -> bf16 (already [N][K] row-major = B^T) ----
__global__ __launch_bounds__(256) void cast_w(const float* __restrict__ W,
                                              unsigned short* __restrict__ Wb) {
    size_t g = (size_t)(blockIdx.x * 256 + threadIdx.x) * 4;
    float4 v = *(const float4*)(W + g);
    *(ushort4*)(Wb + g) = make_ushort4(f2bf(v.x), f2bf(v.y), f2bf(v.z), f2bf(v.w));
}

// ---- kernel 3: C[M,N] = A[M,K] * B[N,K]^T, bf16 in, fp32 out (m97 structure) ----
// Grid: x = bn (8, fastest) so the 8 bn-siblings sharing one A-tile dispatch
// together (one per XCD) -> A fetched from HBM once, served from L3 after.
#define BM 128
#define BN 128
#define BK 32
__global__ __launch_bounds__(256) void gemm_bt(const unsigned short* __restrict__ A,
                                               const unsigned short* __restrict__ B,
                                               float* __restrict__ C) {
    __shared__ unsigned short lA[BM * BK];   // 8 KiB, unpadded (global_load_lds layout)
    __shared__ unsigned short lB[BN * BK];   // 8 KiB

    const int bn = blockIdx.x, bm = blockIdx.y;
    const int tid  = threadIdx.x;
    const int wave = tid >> 6, lane = tid & 63;
    const int wm = (wave >> 1) * 64, wn = (wave & 1) * 64;

    const int lrow = lane >> 2;          // 0..15
    const int lcol = (lane & 3) * 8;     // 0,8,16,24 (bf16 elems)

    const unsigned short* Abase = A + (size_t)bm * 128 * KDIM;
    const unsigned short* Bbase = B + (size_t)bn * 128 * KDIM;

    f32x4 acc[4][4];
#pragma unroll
    for (int i = 0; i < 4; ++i)
#pragma unroll
        for (int j = 0; j < 4; ++j) acc[i][j] = (f32x4){0.f, 0.f, 0.f, 0.f};

    const int mrow = lane & 15;
    const int kq   = (lane >> 4) * 8;    // 0,8,16,24

    for (int k0 = 0; k0 < KDIM; k0 += BK) {
#pragma unroll
        for (int r = 0; r < 2; ++r) {
            int chunk = wave + r * 4;            // 0..7 (1 KiB LDS chunks)
            int row   = chunk * 16 + lrow;       // 0..127
            async_copy16(Abase + (size_t)row * KDIM + k0 + lcol, &lA[chunk * 512 + lane * 8]);
            async_copy16(Bbase + (size_t)row * KDIM + k0 + lcol, &lB[chunk * 512 + lane * 8]);
        }
        __syncthreads();   // drains vmcnt (global_load_lds) + orders LDS

        bf16x8 af[4], bfr[4];
#pragma unroll
        for (int i = 0; i < 4; ++i) {
            af[i]  = *(const bf16x8*)&lA[(wm + i * 16 + mrow) * BK + kq];
            bfr[i] = *(const bf16x8*)&lB[(wn + i * 16 + mrow) * BK + kq];
        }
#pragma unroll
        for (int i = 0; i < 4; ++i)
#pragma unroll
            for (int j = 0; j < 4; ++j)
                acc[i][j] = __builtin_amdgcn_mfma_f32_16x16x32_bf16(af[i], bfr[j], acc[i][j], 0, 0, 0);
        __syncthreads();   // protect LDS before next stage
    }

    // epilogue: C/D layout col=lane&15, row=(lane>>4)*4+reg
    const int col   = lane & 15;
    const int rquad = (lane >> 4) * 4;
#pragma unroll
    for (int i = 0; i < 4; ++i) {
        int gm0 = bm * 128 + wm + i * 16 + rquad;
#pragma unroll
        for (int j = 0; j < 4; ++j) {
            int gn = bn * 128 + wn + j * 16 + col;
#pragma unroll
            for (int rg = 0; rg < 4; ++rg) {
                int gm = gm0 + rg;
                if (gm < MTOK) C[(size_t)gm * NOUT + gn] = acc[i][j][rg];
            }
        }
    }
}

// ---- fallback (ws too small): exact fp32, slow but correct ----
__global__ __launch_bounds__(256) void naive_fb(const float* __restrict__ feats,
                                                const float* __restrict__ W,
                                                float* __restrict__ out) {
    int t = blockIdx.x;
    int o = blockIdx.y * 256 + threadIdx.x;
    int im = 0;
    while (t >= c_mend[im]) im++;
    int r = t - c_moff[im];
    int wp = c_wp[im], wp2 = wp >> 1;
    int i = r / wp2, j = r - i * wp2;
    const float* f00 = feats + (size_t)(c_foff[im] + (2*i)*wp + 2*j) * 1024;
    const float* f10 = f00 + (size_t)wp * 1024;
    const float* w = W + (size_t)o * 4096;
    float s = 0.f;
    for (int d = 0; d < 1024; ++d)
        s += f00[d] * w[d*4] + f00[d+1024] * w[d*4+1] + f10[d] * w[d*4+2] + f10[d+1024] * w[d*4+3];
    out[(size_t)t * 1024 + o] = s;
}

extern "C" void kernel_launch(void* const* d_in, const int* in_sizes, int n_in,
                              void* d_out, int out_size, void* d_ws, size_t ws_size,
                              hipStream_t stream) {
    const float* feats = (const float*)d_in[0];   // [67440, 1024] fp32
    const float* W     = (const float*)d_in[1];   // [1024, 4096] fp32
    float* out         = (float*)d_out;           // [16860, 1024] fp32

    const size_t need = ((size_t)MPAD + 1024) * KDIM * sizeof(unsigned short); // ~147 MB
    if (ws_size >= need) {
        unsigned short* merged = (unsigned short*)d_ws;          // [MPAD, 4096] bf16
        unsigned short* Wb     = merged + (size_t)MPAD * KDIM;   // [1024, 4096] bf16
        merge_cast<<<dim3((MTOK + 3) / 4), 256, 0, stream>>>(feats, merged);
        cast_w<<<dim3((NOUT * KDIM / 4) / 256), 256, 0, stream>>>(W, Wb);
        gemm_bt<<<dim3(NOUT / BN, MPAD / BM), 256, 0, stream>>>(merged, Wb, out);
    } else {
        naive_fb<<<dim3(MTOK, 4), 256, 0, stream>>>(feats, W, out);
    }
}